// Round 2
// 3415.118 us; speedup vs baseline: 1.8715x; 1.8715x over previous
//
#include <hip/hip_runtime.h>
#include <hip/hip_bf16.h>

// ---------------------------------------------------------------------------
// ToyMoE: conv stack -> top-2 gating -> sparse expert MLP -> combine + aux.
// Round 2b: convs 2-5 on MFMA (split-bf16 hi/lo x3 for fp32-class accuracy).
// conv1 (CI=3) stays direct fp32. conv1/conv2 run in two 128-image halves so
// all transformed weights fit INSIDE the existing workspace footprint.
// ---------------------------------------------------------------------------

// memory map (floats). Total footprint unchanged from the passing baseline:
//   [0, 16777216)        c1 half-batch (128*128*32*32)   | later c3/c4/feats/h/eo
//   [16777216, 21200896) wb2..wb5 transformed weights (live whole run)
//   [33554432, 50331648) c2 full batch (256*256*16*16)
//   [50331648, ...)      ctrl block (as before)
#define WS_OFF_C1    ((size_t)0)
#define WS_OFF_C2    ((size_t)33554432)
#define WS_OFF_C3    ((size_t)0)          // 256*256*8*8 = 4,194,304
#define WS_OFF_C4    ((size_t)4194304)    // 256*512*4*4 = 2,097,152
#define WS_OFF_FEATS ((size_t)6291456)    // 256*2048    =   524,288
#define WS_OFF_H     ((size_t)6815744)    // 512*4096    = 2,097,152
#define WS_OFF_EO    ((size_t)8912896)    // 512*1024    =   524,288
#define WS_OFF_WB2   ((size_t)16777216)   // 9*128*256 =   294,912
#define WS_OFF_WB3   ((size_t)17072128)   // 9*256*256 =   589,824
#define WS_OFF_WB4   ((size_t)17661952)   // 9*256*512 = 1,179,648
#define WS_OFF_WB5   ((size_t)18841600)   // 9*512*512 = 2,359,296 (ends 21200896)
#define WS_OFF_CTRL  ((size_t)50331648)

typedef short bf16x8 __attribute__((ext_vector_type(8)));   // 8 bf16 in 4 VGPRs
typedef float f32x16 __attribute__((ext_vector_type(16)));

// ---------------------------------------------------------------------------
// Direct fp32 conv3x3+bias+relu+maxpool (conv1 only, CI=3).
// ---------------------------------------------------------------------------
template<int CI, int CO, int HIN, int WIN, int TP, int PB, int CB>
__global__ __launch_bounds__(256) void conv_pool_kernel(
    const float* __restrict__ in, const float* __restrict__ wgt,
    const float* __restrict__ bias, float* __restrict__ out)
{
    constexpr int PH = HIN / 2, PW = WIN / 2;
    constexpr int IT = 2 * TP + 2;
    constexpr int CT = 2 * PB;
    constexpr int ST = CT + 2;
    constexpr int SW = (CB * 9) | 1;
    constexpr int NTX = PW / TP;

    __shared__ float lin[CB * IT * IT];
    __shared__ float lw[64 * SW];

    const int tid = threadIdx.x;
    const int co  = tid & 63;
    const int tq  = tid >> 6;
    const int b   = blockIdx.z;
    const int co0 = blockIdx.y * 64;
    const int ty  = (blockIdx.x / NTX) * TP;
    const int tx  = (blockIdx.x % NTX) * TP;
    const int py0 = ty + (tq >> 1) * PB;
    const int px0 = tx + (tq & 1) * PB;
    const int oy_base = 2 * (py0 - ty);
    const int ox_base = 2 * (px0 - tx);

    float acc[CT][CT];
    #pragma unroll
    for (int i = 0; i < CT; ++i)
        #pragma unroll
        for (int j = 0; j < CT; ++j) acc[i][j] = 0.f;

    for (int ci0 = 0; ci0 < CI; ci0 += CB) {
        __syncthreads();
        for (int i = tid; i < CB * IT * IT; i += 256) {
            int ci = i / (IT * IT);
            int r  = i % (IT * IT);
            int iy = r / IT, ix = r % IT;
            int gy = 2 * ty - 1 + iy, gx = 2 * tx - 1 + ix;
            float v = 0.f;
            if (gy >= 0 && gy < HIN && gx >= 0 && gx < WIN)
                v = in[(((size_t)b * CI + ci0 + ci) * HIN + gy) * WIN + gx];
            lin[i] = v;
        }
        for (int i = tid; i < 64 * CB * 9; i += 256) {
            int c = i / (CB * 9);
            int r = i % (CB * 9);
            lw[c * SW + r] = wgt[(((size_t)(co0 + c)) * CI + ci0) * 9 + r];
        }
        __syncthreads();

        #pragma unroll 1
        for (int ci = 0; ci < CB; ++ci) {
            float wr[9];
            #pragma unroll
            for (int k = 0; k < 9; ++k) wr[k] = lw[co * SW + ci * 9 + k];
            const float* base = &lin[ci * IT * IT];
            #pragma unroll
            for (int iy = 0; iy < ST; ++iy) {
                float row[ST];
                #pragma unroll
                for (int j = 0; j < ST; ++j)
                    row[j] = base[(oy_base + iy) * IT + ox_base + j];
                #pragma unroll
                for (int ky = 0; ky < 3; ++ky) {
                    const int oy = iy - ky;
                    if (oy >= 0 && oy < CT) {
                        #pragma unroll
                        for (int kx = 0; kx < 3; ++kx)
                            #pragma unroll
                            for (int ox = 0; ox < CT; ++ox)
                                acc[oy][ox] = fmaf(wr[ky * 3 + kx], row[ox + kx], acc[oy][ox]);
                    }
                }
            }
        }
    }

    const float bv = bias[co0 + co];
    #pragma unroll
    for (int py = 0; py < PB; ++py)
        #pragma unroll
        for (int px = 0; px < PB; ++px) {
            float m = fmaxf(fmaxf(acc[2*py][2*px],   acc[2*py][2*px+1]),
                            fmaxf(acc[2*py+1][2*px], acc[2*py+1][2*px+1]));
            m = fmaxf(m + bv, 0.f);
            out[(((size_t)b * CO + co0 + co) * PH + py0 + py) * PW + px0 + px] = m;
        }
}

// ---------------------------------------------------------------------------
// Weight transform: w[co][ci][3][3] fp32 -> fragment-linear bf16 hi/lo.
// Per frag (tap, kc(16-ci chunk), cg(32-co)): 64 lanes x 32B:
//   [lane*32 + 0..15]  hi bf16 x8  (k = kc*16 + (lane>>5)*8 + j, co = cg*32 + (lane&31))
//   [lane*32 + 16..31] lo bf16 x8
// ---------------------------------------------------------------------------
template<int CI, int CO>
__global__ __launch_bounds__(256) void wtrans_kernel(
    const float* __restrict__ w, unsigned int* __restrict__ wt)
{
    constexpr int KC = CI / 16, CG = CO / 32;
    constexpr int TOT = 9 * KC * CG * 64;
    int gid = blockIdx.x * 256 + threadIdx.x;
    if (gid >= TOT) return;
    int lane = gid & 63;
    int f3   = gid >> 6;              // (tap*KC + kc)*CG + cg
    int cg   = f3 % CG;
    int tkc  = f3 / CG;
    int kc   = tkc % KC;
    int tap  = tkc / KC;
    int co   = cg * 32 + (lane & 31);
    int cib  = kc * 16 + (lane >> 5) * 8;

    unsigned int hv[4], lv[4];
    #pragma unroll
    for (int jj = 0; jj < 4; ++jj) {
        unsigned int hh = 0, ll = 0;
        #pragma unroll
        for (int k = 0; k < 2; ++k) {
            int j = jj * 2 + k;
            float v = w[((size_t)co * CI + cib + j) * 9 + tap];
            unsigned int u  = __builtin_bit_cast(unsigned int, v);
            unsigned int hr = (u + 0x7fffu + ((u >> 16) & 1u)) >> 16;
            float hf = __builtin_bit_cast(float, hr << 16);
            float lw_ = v - hf;
            unsigned int ul = __builtin_bit_cast(unsigned int, lw_);
            unsigned int lr = (ul + 0x7fffu + ((ul >> 16) & 1u)) >> 16;
            hh |= hr << (16 * k);
            ll |= lr << (16 * k);
        }
        hv[jj] = hh; lv[jj] = ll;
    }
    unsigned int* dst = wt + (size_t)gid * 8;
    dst[0] = hv[0]; dst[1] = hv[1]; dst[2] = hv[2]; dst[3] = hv[3];
    dst[4] = lv[0]; dst[5] = lv[1]; dst[6] = lv[2]; dst[7] = lv[3];
}

// ---------------------------------------------------------------------------
// MFMA implicit-GEMM conv3x3(SAME)+bias+relu+maxpool2, split-bf16 (hi/lo).
//   block = 256 threads = 4 waves; tile = 256 conv px x 64 co.
//   wave = 64 px x 64 co = 2x2 frags of v_mfma_f32_32x32x16_bf16.
//   acc += a_lo*b_hi + a_hi*b_lo + a_hi*b_hi   (a_lo*b_lo ~2^-18, dropped)
// LDS: halo tile, pixel-major, 136B stride: [px][hi x32 | lo x32 | 8B pad].
// 34 words == 2 banks mod 32 -> staging writes and b64 frag reads ~2-way.
// B-frags: coalesced dwordx4 from pre-transformed global (L2-hot).
// TH*TW*NIMG == 256 required.
// ---------------------------------------------------------------------------
template<int CI, int CO, int H, int TH, int TW, int NIMG>
__global__ __launch_bounds__(256) void conv_mfma_kernel(
    const float* __restrict__ in, const uint4* __restrict__ wt,
    const float* __restrict__ bias, float* __restrict__ out)
{
    constexpr int Wd  = H;
    constexpr int PH  = H / 2, PW = H / 2;
    constexpr int HY  = TH + 2, HX = TW + 2;
    constexpr int NH1 = HY * HX;
    constexpr int NHT = NH1 * NIMG;
    constexpr int PST = 136;
    constexpr int KC  = CI / 16;
    constexpr int CG  = CO / 32;
    constexpr int NCC = CI / 32;

    __shared__ char lds[NHT * PST];

    const int tid  = threadIdx.x;
    const int lane = tid & 63;
    const int wv   = tid >> 6;
    const int hi1  = lane >> 5;
    const int cg0  = blockIdx.x * 2;
    const int ty0  = blockIdx.y * TH;
    const int imgb = blockIdx.z * NIMG;

    // A-fragment base LDS byte addrs (tap (0,0)); taps add imm offsets.
    int abase[2];
    #pragma unroll
    for (int f = 0; f < 2; ++f) {
        int q  = wv * 64 + f * 32 + (lane & 31);   // block pixel index = A row
        int im = q / (TH * TW);
        int p  = q % (TH * TW);
        int py = p / TW, px = p % TW;
        abase[f] = (im * NH1 + py * HX + px) * PST + hi1 * 16;
    }

    f32x16 zero16;
    #pragma unroll
    for (int k = 0; k < 16; ++k) zero16[k] = 0.f;
    f32x16 acc[2][2];
    #pragma unroll
    for (int f = 0; f < 2; ++f)
        #pragma unroll
        for (int g = 0; g < 2; ++g) acc[f][g] = zero16;

    #pragma unroll 1
    for (int cc = 0; cc < NCC; ++cc) {
        __syncthreads();
        // stage halo tile for this 32-ci chunk, split fp32 -> hi/lo bf16
        #pragma unroll 4
        for (int idx = tid; idx < NHT * 32; idx += 256) {
            int ci = idx / NHT;
            int hp = idx - ci * NHT;
            int im = hp / NH1;
            int r  = hp - im * NH1;
            int hy = r / HX, hx = r - hy * HX;
            int gy = ty0 - 1 + hy, gx = hx - 1;
            float v = 0.f;
            if (gy >= 0 && gy < H && gx >= 0 && gx < Wd)
                v = in[(((size_t)(imgb + im) * CI + cc * 32 + ci) * H + gy) * Wd + gx];
            unsigned int u  = __builtin_bit_cast(unsigned int, v);
            unsigned int hr = (u + 0x7fffu + ((u >> 16) & 1u)) >> 16;
            float hf = __builtin_bit_cast(float, hr << 16);
            float lo = v - hf;
            unsigned int ul = __builtin_bit_cast(unsigned int, lo);
            unsigned int lr = (ul + 0x7fffu + ((ul >> 16) & 1u)) >> 16;
            char* base = lds + hp * PST + ci * 2;
            *(unsigned short*)(base)      = (unsigned short)hr;
            *(unsigned short*)(base + 64) = (unsigned short)lr;
        }
        __syncthreads();

        // 9 taps x (B frag global loads + A frag LDS loads + 24 MFMA)
        #pragma unroll
        for (int ky = 0; ky < 3; ++ky)
        #pragma unroll
        for (int kx = 0; kx < 3; ++kx) {
            const int toff = (ky * HX + kx) * PST;
            uint4 bh[2][2], bl[2][2];           // [k-step][n-frag]
            #pragma unroll
            for (int ks = 0; ks < 2; ++ks)
                #pragma unroll
                for (int g = 0; g < 2; ++g) {
                    const int flat = ((ky * 3 + kx) * KC + cc * 2 + ks) * CG + cg0 + g;
                    bh[ks][g] = wt[(size_t)flat * 128 + lane * 2];
                    bl[ks][g] = wt[(size_t)flat * 128 + lane * 2 + 1];
                }
            #pragma unroll
            for (int f = 0; f < 2; ++f) {
                const char* ap = lds + abase[f] + toff;
                uint2 h0a = *(const uint2*)(ap);
                uint2 h0b = *(const uint2*)(ap + 8);
                uint2 h1a = *(const uint2*)(ap + 32);
                uint2 h1b = *(const uint2*)(ap + 40);
                uint2 l0a = *(const uint2*)(ap + 64);
                uint2 l0b = *(const uint2*)(ap + 72);
                uint2 l1a = *(const uint2*)(ap + 96);
                uint2 l1b = *(const uint2*)(ap + 104);
                bf16x8 ah0 = __builtin_bit_cast(bf16x8, make_uint4(h0a.x, h0a.y, h0b.x, h0b.y));
                bf16x8 ah1 = __builtin_bit_cast(bf16x8, make_uint4(h1a.x, h1a.y, h1b.x, h1b.y));
                bf16x8 al0 = __builtin_bit_cast(bf16x8, make_uint4(l0a.x, l0a.y, l0b.x, l0b.y));
                bf16x8 al1 = __builtin_bit_cast(bf16x8, make_uint4(l1a.x, l1a.y, l1b.x, l1b.y));
                #pragma unroll
                for (int g = 0; g < 2; ++g) {
                    bf16x8 bh0 = __builtin_bit_cast(bf16x8, bh[0][g]);
                    bf16x8 bl0 = __builtin_bit_cast(bf16x8, bl[0][g]);
                    bf16x8 bh1 = __builtin_bit_cast(bf16x8, bh[1][g]);
                    bf16x8 bl1 = __builtin_bit_cast(bf16x8, bl[1][g]);
                    acc[f][g] = __builtin_amdgcn_mfma_f32_32x32x16_bf16(al0, bh0, acc[f][g], 0, 0, 0);
                    acc[f][g] = __builtin_amdgcn_mfma_f32_32x32x16_bf16(ah0, bl0, acc[f][g], 0, 0, 0);
                    acc[f][g] = __builtin_amdgcn_mfma_f32_32x32x16_bf16(ah0, bh0, acc[f][g], 0, 0, 0);
                    acc[f][g] = __builtin_amdgcn_mfma_f32_32x32x16_bf16(al1, bh1, acc[f][g], 0, 0, 0);
                    acc[f][g] = __builtin_amdgcn_mfma_f32_32x32x16_bf16(ah1, bl1, acc[f][g], 0, 0, 0);
                    acc[f][g] = __builtin_amdgcn_mfma_f32_32x32x16_bf16(ah1, bh1, acc[f][g], 0, 0, 0);
                }
            }
        }
    }

    // epilogue: 2x2 maxpool + bias + relu + store (NCHW fp32).
    // D-frag: col(co) = lane&31, row m = (r&3) + 8*(r>>2) + 4*hi1, r in [0,16).
    #pragma unroll
    for (int g = 0; g < 2; ++g) {
        const int co = (cg0 + g) * 32 + (lane & 31);
        const float bv = bias[co];
        if constexpr (TW == 32) {
            // pixel rows py = wv*2 + f; px = m. Vertical pool across f.
            const size_t ob = ((size_t)imgb * CO + co) * (PH * PW)
                            + (size_t)(ty0 / 2 + wv) * PW;
            #pragma unroll
            for (int rh = 0; rh < 8; ++rh) {
                const int r = 2 * rh;
                float m = fmaxf(fmaxf(acc[0][g][r], acc[0][g][r + 1]),
                                fmaxf(acc[1][g][r], acc[1][g][r + 1]));
                m = fmaxf(m + bv, 0.f);
                const int pxo = (rh & 1) + 4 * (rh >> 1) + 2 * hi1;
                out[ob + pxo] = m;
            }
        } else if constexpr (TW == 16) {
            // py = wv*4 + f*2 + (m>=16); vertical pool r <-> r+8.
            #pragma unroll
            for (int f = 0; f < 2; ++f) {
                const size_t ob = ((size_t)imgb * CO + co) * (PH * PW)
                                + (size_t)(wv * 2 + f) * PW;
                #pragma unroll
                for (int rh = 0; rh < 4; ++rh) {
                    const int r = 2 * rh;
                    float m = fmaxf(fmaxf(acc[f][g][r],     acc[f][g][r + 1]),
                                    fmaxf(acc[f][g][r + 8], acc[f][g][r + 9]));
                    m = fmaxf(m + bv, 0.f);
                    const int pxo = (rh & 1) + 4 * (rh >> 1) + 2 * hi1;
                    out[ob + pxo] = m;
                }
            }
        } else if constexpr (TW == 8) {
            // image = wv; py = f*4 + (r>>2); vertical pool r <-> r+4.
            const int im = imgb + wv;
            #pragma unroll
            for (int f = 0; f < 2; ++f)
                #pragma unroll
                for (int rr = 0; rr < 4; ++rr) {
                    const int r = (rr & 1) * 2 + (rr >> 1) * 8;  // {0,2,8,10}
                    float m = fmaxf(fmaxf(acc[f][g][r],     acc[f][g][r + 1]),
                                    fmaxf(acc[f][g][r + 4], acc[f][g][r + 5]));
                    m = fmaxf(m + bv, 0.f);
                    const int pyo = 2 * f + (r >> 3);
                    const int pxo = ((r >> 1) & 1) + 2 * hi1;
                    out[((size_t)im * CO + co) * 16 + pyo * 4 + pxo] = m;
                }
        } else {  // TW == 4: vertical partner is lane^32 (py lsb = hi1)
            #pragma unroll
            for (int f = 0; f < 2; ++f)
                #pragma unroll
                for (int rh = 0; rh < 8; ++rh) {
                    const int r = 2 * rh;
                    float m01 = fmaxf(acc[f][g][r], acc[f][g][r + 1]);
                    float mo  = __shfl_xor(m01, 32, 64);
                    float m   = fmaxf(fmaxf(m01, mo) + bv, 0.f);
                    if (hi1 == 0) {
                        const int im  = imgb + wv * 4 + f * 2 + (r >> 3);
                        const int pyo = (r >> 2) & 1;
                        const int pxo = (r >> 1) & 1;
                        out[((size_t)im * CO + co) * 4 + pyo * 2 + pxo] = m;
                    }
                }
        }
    }
}

// ---------------------------------------------------------------------------
// Gating: one block per token.
// ---------------------------------------------------------------------------
__global__ __launch_bounds__(256) void gating_kernel(
    const float* __restrict__ feats, const float* __restrict__ wg,
    int* __restrict__ top2idx, float* __restrict__ top2gate,
    int* __restrict__ counts, int* __restrict__ loadcnt,
    float* __restrict__ importance)
{
    __shared__ float red[256 * 17];
    const int b = blockIdx.x, tid = threadIdx.x;
    float acc[16];
    #pragma unroll
    for (int e = 0; e < 16; ++e) acc[e] = 0.f;

    #pragma unroll
    for (int it = 0; it < 8; ++it) {
        int d = tid + it * 256;
        float f = feats[(size_t)b * 2048 + d];
        const float4* w4 = (const float4*)(wg + (size_t)d * 16);
        float4 a = w4[0], c = w4[1], dd = w4[2], g = w4[3];
        acc[0]  = fmaf(f, a.x, acc[0]);  acc[1]  = fmaf(f, a.y, acc[1]);
        acc[2]  = fmaf(f, a.z, acc[2]);  acc[3]  = fmaf(f, a.w, acc[3]);
        acc[4]  = fmaf(f, c.x, acc[4]);  acc[5]  = fmaf(f, c.y, acc[5]);
        acc[6]  = fmaf(f, c.z, acc[6]);  acc[7]  = fmaf(f, c.w, acc[7]);
        acc[8]  = fmaf(f, dd.x, acc[8]); acc[9]  = fmaf(f, dd.y, acc[9]);
        acc[10] = fmaf(f, dd.z, acc[10]);acc[11] = fmaf(f, dd.w, acc[11]);
        acc[12] = fmaf(f, g.x, acc[12]); acc[13] = fmaf(f, g.y, acc[13]);
        acc[14] = fmaf(f, g.z, acc[14]); acc[15] = fmaf(f, g.w, acc[15]);
    }
    #pragma unroll
    for (int e = 0; e < 16; ++e) red[tid * 17 + e] = acc[e];
    __syncthreads();
    for (int s = 128; s >= 1; s >>= 1) {
        if (tid < s) {
            #pragma unroll
            for (int e = 0; e < 16; ++e)
                red[tid * 17 + e] += red[(tid + s) * 17 + e];
        }
        __syncthreads();
    }
    if (tid == 0) {
        float l[16];
        #pragma unroll
        for (int e = 0; e < 16; ++e) l[e] = red[e];
        int i0 = 0;
        for (int e = 1; e < 16; ++e) if (l[e] > l[i0]) i0 = e;
        int i1 = -1;
        for (int e = 0; e < 16; ++e) {
            if (e == i0) continue;
            if (i1 < 0 || l[e] > l[i1]) i1 = e;
        }
        float t  = expf(l[i1] - l[i0]);
        float g0 = 1.f / (1.f + t);
        float g1 = t / (1.f + t);
        top2idx[2 * b]     = i0;
        top2idx[2 * b + 1] = i1;
        top2gate[2 * b]     = g0;
        top2gate[2 * b + 1] = g1;
        atomicAdd(&importance[i0], g0);
        atomicAdd(&importance[i1], g1);
        atomicAdd(&counts[i0], 1);
        atomicAdd(&counts[i1], 1);
        if (g0 > 0.f) atomicAdd(&loadcnt[i0], 1);
        if (g1 > 0.f) atomicAdd(&loadcnt[i1], 1);
    }
}

// ---------------------------------------------------------------------------
__global__ __launch_bounds__(512) void finalize_kernel(
    const int* __restrict__ counts, const int* __restrict__ loadcnt,
    const float* __restrict__ importance, const int* __restrict__ top2idx,
    int* __restrict__ goff, int* __restrict__ pair_token,
    int* __restrict__ pair_of_token, float* __restrict__ out_aux)
{
    __shared__ int s_off[17];
    __shared__ int s_cur[16];
    const int tid = threadIdx.x;
    if (tid < 16) s_cur[tid] = 0;
    if (tid == 0) {
        int o = 0;
        for (int e = 0; e < 16; ++e) { s_off[e] = o; o += counts[e]; }
        s_off[16] = o;
        float mi = 0.f, ml = 0.f;
        for (int e = 0; e < 16; ++e) { mi += importance[e]; ml += (float)loadcnt[e]; }
        mi *= (1.f / 16.f); ml *= (1.f / 16.f);
        float vi = 0.f, vl = 0.f;
        for (int e = 0; e < 16; ++e) {
            float di = importance[e] - mi; vi += di * di;
            float dl = (float)loadcnt[e] - ml; vl += dl * dl;
        }
        vi *= (1.f / 16.f); vl *= (1.f / 16.f);
        out_aux[0] = 0.01f * (vi / (mi * mi + 1e-10f) + vl / (ml * ml + 1e-10f));
    }
    __syncthreads();
    if (tid < 17) goff[tid] = s_off[tid];
    const int e   = top2idx[tid];
    const int pos = atomicAdd(&s_cur[e], 1);
    const int pair = s_off[e] + pos;
    pair_token[pair]    = tid >> 1;
    pair_of_token[tid]  = pair;
}

// ---------------------------------------------------------------------------
template<int D, int N, bool RELU, bool GATHER>
__global__ __launch_bounds__(256) void fc_kernel(
    const float* __restrict__ X, const float* __restrict__ W,
    const float* __restrict__ bias, float* __restrict__ Y,
    const int* __restrict__ pair_token, const int* __restrict__ goff,
    const int* __restrict__ counts)
{
    const int e   = blockIdx.z;
    const int n_e = counts[e];
    const int t0  = blockIdx.y * 32;
    if (t0 >= n_e) return;
    const int nb  = blockIdx.x * 128;
    const int off = goff[e];
    const float* We = W + (size_t)e * D * N;
    const float* be = bias + (size_t)e * N;

    __shared__ __align__(16) float Xt[32 * 36];
    __shared__ __align__(16) float Wt[32 * 132];
    __shared__ int rowidx[32];

    const int tid = threadIdx.x;
    const int thr_tok = tid >> 5;
    const int thr_n   = tid & 31;

    if (tid < 32) {
        int tt = min(t0 + tid, n_e - 1);
        rowidx[tid] = GATHER ? pair_token[off + tt] : (off + tt);
    }
    __syncthreads();

    float acc[4][4];
    #pragma unroll
    for (int i = 0; i < 4; ++i)
        #pragma unroll
        for (int j = 0; j < 4; ++j) acc[i][j] = 0.f;

    for (int d0 = 0; d0 < D; d0 += 32) {
        for (int i = tid; i < 1024; i += 256) {
            int t = i >> 5, dd = i & 31;
            Xt[dd * 36 + t] = X[(size_t)rowidx[t] * D + d0 + dd];
        }
        for (int i = tid; i < 4096; i += 256) {
            int dd = i >> 7, n = i & 127;
            Wt[dd * 132 + n] = We[(size_t)(d0 + dd) * N + nb + n];
        }
        __syncthreads();
        #pragma unroll
        for (int dd = 0; dd < 32; ++dd) {
            float4 xv = *(const float4*)&Xt[dd * 36 + thr_tok * 4];
            float4 wv = *(const float4*)&Wt[dd * 132 + thr_n * 4];
            acc[0][0] = fmaf(xv.x, wv.x, acc[0][0]);
            acc[0][1] = fmaf(xv.x, wv.y, acc[0][1]);
            acc[0][2] = fmaf(xv.x, wv.z, acc[0][2]);
            acc[0][3] = fmaf(xv.x, wv.w, acc[0][3]);
            acc[1][0] = fmaf(xv.y, wv.x, acc[1][0]);
            acc[1][1] = fmaf(xv.y, wv.y, acc[1][1]);
            acc[1][2] = fmaf(xv.y, wv.z, acc[1][2]);
            acc[1][3] = fmaf(xv.y, wv.w, acc[1][3]);
            acc[2][0] = fmaf(xv.z, wv.x, acc[2][0]);
            acc[2][1] = fmaf(xv.z, wv.y, acc[2][1]);
            acc[2][2] = fmaf(xv.z, wv.z, acc[2][2]);
            acc[2][3] = fmaf(xv.z, wv.w, acc[2][3]);
            acc[3][0] = fmaf(xv.w, wv.x, acc[3][0]);
            acc[3][1] = fmaf(xv.w, wv.y, acc[3][1]);
            acc[3][2] = fmaf(xv.w, wv.z, acc[3][2]);
            acc[3][3] = fmaf(xv.w, wv.w, acc[3][3]);
        }
        __syncthreads();
    }

    const float4 bvv = *(const float4*)&be[nb + thr_n * 4];
    #pragma unroll
    for (int i = 0; i < 4; ++i) {
        int t = t0 + thr_tok * 4 + i;
        if (t < n_e) {
            float4 v;
            v.x = acc[i][0] + bvv.x;
            v.y = acc[i][1] + bvv.y;
            v.z = acc[i][2] + bvv.z;
            v.w = acc[i][3] + bvv.w;
            if (RELU) {
                v.x = fmaxf(v.x, 0.f); v.y = fmaxf(v.y, 0.f);
                v.z = fmaxf(v.z, 0.f); v.w = fmaxf(v.w, 0.f);
            }
            *(float4*)&Y[(size_t)(off + t) * N + nb + thr_n * 4] = v;
        }
    }
}

// ---------------------------------------------------------------------------
__global__ __launch_bounds__(256) void softmax_kernel(float* __restrict__ eo)
{
    const int p = blockIdx.x, tid = threadIdx.x;
    float* x = eo + (size_t)p * 1024;
    float v[4];
    #pragma unroll
    for (int k = 0; k < 4; ++k) v[k] = x[tid + k * 256];
    float m = fmaxf(fmaxf(v[0], v[1]), fmaxf(v[2], v[3]));
    __shared__ float s[256];
    s[tid] = m; __syncthreads();
    for (int st = 128; st >= 1; st >>= 1) {
        if (tid < st) s[tid] = fmaxf(s[tid], s[tid + st]);
        __syncthreads();
    }
    m = s[0]; __syncthreads();
    float ex[4]; float sum = 0.f;
    #pragma unroll
    for (int k = 0; k < 4; ++k) { ex[k] = expf(v[k] - m); sum += ex[k]; }
    s[tid] = sum; __syncthreads();
    for (int st = 128; st >= 1; st >>= 1) {
        if (tid < st) s[tid] += s[tid + st];
        __syncthreads();
    }
    const float inv = 1.f / s[0];
    #pragma unroll
    for (int k = 0; k < 4; ++k) x[tid + k * 256] = ex[k] * inv;
}

// ---------------------------------------------------------------------------
__global__ __launch_bounds__(256) void combine_kernel(
    const float* __restrict__ eo, const int* __restrict__ pair_of_token,
    const float* __restrict__ top2gate, float* __restrict__ y)
{
    const int b = blockIdx.x, tid = threadIdx.x;
    const int p0 = pair_of_token[2 * b], p1 = pair_of_token[2 * b + 1];
    const float g0 = top2gate[2 * b], g1 = top2gate[2 * b + 1];
    #pragma unroll
    for (int k = 0; k < 4; ++k) {
        int o = tid + k * 256;
        y[(size_t)b * 1024 + o] =
            g0 * eo[(size_t)p0 * 1024 + o] + g1 * eo[(size_t)p1 * 1024 + o];
    }
}

// ---------------------------------------------------------------------------
extern "C" void kernel_launch(void* const* d_in, const int* in_sizes, int n_in,
                              void* d_out, int out_size, void* d_ws, size_t ws_size,
                              hipStream_t stream)
{
    const float* x      = (const float*)d_in[0];
    const float* cw1    = (const float*)d_in[1];
    const float* cb1    = (const float*)d_in[2];
    const float* cw2    = (const float*)d_in[3];
    const float* cb2    = (const float*)d_in[4];
    const float* cw3    = (const float*)d_in[5];
    const float* cb3    = (const float*)d_in[6];
    const float* cw4    = (const float*)d_in[7];
    const float* cb4    = (const float*)d_in[8];
    const float* cw5    = (const float*)d_in[9];
    const float* cb5    = (const float*)d_in[10];
    const float* w1     = (const float*)d_in[11];
    const float* b1     = (const float*)d_in[12];
    const float* w2     = (const float*)d_in[13];
    const float* b2     = (const float*)d_in[14];
    const float* w_gate = (const float*)d_in[15];

    float* wsf   = (float*)d_ws;
    float* c1    = wsf + WS_OFF_C1;
    float* c2    = wsf + WS_OFF_C2;
    float* c3    = wsf + WS_OFF_C3;
    float* c4    = wsf + WS_OFF_C4;
    float* feats = wsf + WS_OFF_FEATS;
    float* h     = wsf + WS_OFF_H;
    float* eo    = wsf + WS_OFF_EO;
    float* wb2   = wsf + WS_OFF_WB2;
    float* wb3   = wsf + WS_OFF_WB3;
    float* wb4   = wsf + WS_OFF_WB4;
    float* wb5   = wsf + WS_OFF_WB5;

    int*   ctrl_i       = (int*)(wsf + WS_OFF_CTRL);
    int*   counts       = ctrl_i;
    int*   loadcnt      = ctrl_i + 16;
    int*   goff         = ctrl_i + 32;
    int*   top2idx      = ctrl_i + 64;
    int*   pair_token   = ctrl_i + 576;
    int*   pair_of      = ctrl_i + 1088;
    float* ctrl_f       = wsf + WS_OFF_CTRL + 2048;
    float* importance   = ctrl_f;
    float* top2gate     = ctrl_f + 16;

    float* y_out   = (float*)d_out;
    float* aux_out = y_out + 256 * 1024;

    hipMemsetAsync(counts, 0, 32 * sizeof(int), stream);
    hipMemsetAsync(importance, 0, 16 * sizeof(float), stream);

    // all weight transforms up-front (targets disjoint from everything live)
    wtrans_kernel<128, 256><<<144,  256, 0, stream>>>(cw2, (unsigned int*)wb2);
    wtrans_kernel<256, 256><<<288,  256, 0, stream>>>(cw3, (unsigned int*)wb3);
    wtrans_kernel<256, 512><<<576,  256, 0, stream>>>(cw4, (unsigned int*)wb4);
    wtrans_kernel<512, 512><<<1152, 256, 0, stream>>>(cw5, (unsigned int*)wb5);

    // conv1 + conv2 in two 128-image halves (c1 half-batch buffer)
    for (int half = 0; half < 2; ++half) {
        const float* xh  = x + (size_t)half * 128 * 3 * 64 * 64;
        float*       c2h = c2 + (size_t)half * 128 * 256 * 16 * 16;
        conv_pool_kernel<3, 128, 64, 64, 8, 4, 3><<<dim3(16, 2, 128), 256, 0, stream>>>(
            xh, cw1, cb1, c1);
        conv_mfma_kernel<128, 256, 32, 8, 32, 1><<<dim3(4, 4, 128), 256, 0, stream>>>(
            c1, (const uint4*)wb2, cb2, c2h);
    }

    // conv3..conv5: MFMA implicit GEMM, split-bf16
    conv_mfma_kernel<256, 256, 16, 16, 16, 1><<<dim3(4, 1, 256), 256, 0, stream>>>(
        c2, (const uint4*)wb3, cb3, c3);
    conv_mfma_kernel<256, 512, 8, 8, 8, 4><<<dim3(8, 1, 64), 256, 0, stream>>>(
        c3, (const uint4*)wb4, cb4, c4);
    conv_mfma_kernel<512, 512, 4, 4, 4, 16><<<dim3(8, 1, 16), 256, 0, stream>>>(
        c4, (const uint4*)wb5, cb5, feats);

    // gating + dispatch + aux
    gating_kernel<<<256, 256, 0, stream>>>(feats, w_gate, top2idx, top2gate,
                                           counts, loadcnt, importance);
    finalize_kernel<<<1, 512, 0, stream>>>(counts, loadcnt, importance, top2idx,
                                           goff, pair_token, pair_of, aux_out);

    // sparse expert MLPs
    fc_kernel<2048, 4096, true,  true ><<<dim3(32, 8, 16), 256, 0, stream>>>(
        feats, w1, b1, h, pair_token, goff, counts);
    fc_kernel<4096, 1024, false, false><<<dim3(8,  8, 16), 256, 0, stream>>>(
        h, w2, b2, eo, pair_token, goff, counts);

    softmax_kernel<<<512, 256, 0, stream>>>(eo);
    combine_kernel<<<256, 256, 0, stream>>>(eo, pair_of, top2gate, y_out);
}